// Round 9
// baseline (259.210 us; speedup 1.0000x reference)
//
#include <hip/hip_runtime.h>
#include <hip/hip_bf16.h>
#include <stdint.h>
#include <math.h>

#define CH 256

typedef __attribute__((ext_vector_type(8)))  short short8;
typedef __attribute__((ext_vector_type(16))) short short16;
typedef __attribute__((ext_vector_type(4)))  float f32x4;

#define GL2LDS16(g, l) __builtin_amdgcn_global_load_lds(                       \
    (const __attribute__((address_space(1))) void*)(g),                        \
    (__attribute__((address_space(3))) void*)(l), 16, 0, 0)

__device__ inline short f2bf(float f) {
    __hip_bfloat16 h = __float2bfloat16(f);
    short s;
    __builtin_memcpy(&s, &h, 2);
    return s;
}

__device__ inline float bf2f(short s) {
    unsigned u = ((unsigned)(unsigned short)s) << 16;
    float f;
    __builtin_memcpy(&f, &u, 4);
    return f;
}

__device__ inline float warp_sum64(float v) {
    v += __shfl_xor(v, 32, 64);
    v += __shfl_xor(v, 16, 64);
    v += __shfl_xor(v, 8, 64);
    v += __shfl_xor(v, 4, 64);
    v += __shfl_xor(v, 2, 64);
    v += __shfl_xor(v, 1, 64);
    return v;
}

__device__ inline float warp_max64(float v) {
    v = fmaxf(v, __shfl_xor(v, 32, 64));
    v = fmaxf(v, __shfl_xor(v, 16, 64));
    v = fmaxf(v, __shfl_xor(v, 8, 64));
    v = fmaxf(v, __shfl_xor(v, 4, 64));
    v = fmaxf(v, __shfl_xor(v, 2, 64));
    v = fmaxf(v, __shfl_xor(v, 1, 64));
    return v;
}

// ==================================================================== MFMA GEMM
// BMxBN tile, BK=64, 2x2 wave grid, 16x16x32 bf16 MFMA. Single-buffer
// 2-barrier K-loop (R12 dbuf regressed; implicit wave overlap suffices).
// R16: Wo GEMM folded into MLP1 via precomputed W2f = Wo @ Wn1_bot.
// R17: W2f fuse restructured (16 blocks x 16 cols, LDS-broadcast inner loop)
//      — R16's 256-block uncoalesced Wo gather was the regression cause.
// EPI 1: GroupNorm(8 cols)+ReLU -> bf16 Cbf only. EPI 0: f32 C/res/bf16 Cbf.
// DUAL : blocks with by >= y_split run the Q GEMM (A2/Bt2/bias2/Cbf2).
// VB   : V-panel column sums atomically into vbar (KV path).
// FILL : edge-role blocks with logical bx==0 scatter rows into elist.
// SCAN : extra grid row runs the CSR prefix scan concurrently. [R11]
// PAN2 : block computes TWO output panels (cols c, c+256) per A staging. [R11]
// XSWZ : XCD-aware remap — ids {h,h+8,h+16,h+24} (same XCD under round-robin)
//        share logical row-panel lby -> A re-reads are L2 hits. [R14]
struct GArgs {
    const short* A; const short* Bt; const float* bias; const float* res;
    float* C; short* Cbf;
    const float* gamma; const float* beta; float* vbar;
    int M, K, Nc, ldc, coff;
    const short* A2; const short* Bt2; const float* bias2; short* Cbf2;
    int M2, Nc2, y_split;
    const int* coli;
    int* cursor; int* elist;
    const int* counts; int* offsets; int Nn;   // SCAN role
};

template <int BM, int BN, int EPI, int DUAL, int VB, int FILL,
          int SCAN = 0, int PAN2 = 0, int XSWZ = 0>
__global__ __launch_bounds__(256) void mfma_gemm(GArgs g)
{
    constexpr int BK = 64;
    constexpr int HM = BM / 2, HN = BN / 2;
    constexpr int FM = HM / 16, FN = HN / 16;
    constexpr int PA = BM / 32;
    constexpr int PB = BN / 32;
    constexpr int NP2 = PAN2 ? 2 : 1;
    __shared__ short As[BM * BK];
    __shared__ short Bs[NP2 * BN * BK];

    const short* A = g.A; const short* Bt = g.Bt;
    const float* bias = g.bias; const float* res = g.res;
    float* C = g.C; short* Cbf = g.Cbf;
    int M = g.M, ldc = g.ldc, co = g.coff;
    const int K = g.K;
    int by = blockIdx.y, bx = blockIdx.x;

    if constexpr (SCAN) {
        if (by == (int)gridDim.y - 1) {
            const int t0 = threadIdx.x;
            if (bx == 0) {
                int* ss = (int*)As;
                int base8 = t0 * 8;
                int loc[8]; int srun = 0;
                #pragma unroll
                for (int j = 0; j < 8; j++) {
                    int idx = base8 + j;
                    int c = (idx < g.Nn) ? g.counts[idx] : 0;
                    loc[j] = srun; srun += c;
                }
                ss[t0] = srun;
                __syncthreads();
                for (int off = 1; off < 256; off <<= 1) {
                    int v = (t0 >= off) ? ss[t0 - off] : 0;
                    __syncthreads();
                    ss[t0] += v;
                    __syncthreads();
                }
                int excl = (t0 > 0) ? ss[t0 - 1] : 0;
                #pragma unroll
                for (int j = 0; j < 8; j++) {
                    int idx = base8 + j;
                    if (idx < g.Nn) {
                        int v = excl + loc[j];
                        g.offsets[idx] = v;
                        g.cursor[idx]  = v;
                    }
                }
                if (t0 == 255) g.offsets[g.Nn] = ss[255];
            }
            return;
        }
    }

    bool qrole = false;
    if constexpr (DUAL) {
        if (by >= g.y_split) {
            by -= g.y_split;
            if (bx * BN >= g.Nc2) return;
            qrole = true;
            A = g.A2; Bt = g.Bt2; bias = g.bias2; Cbf = g.Cbf2;
            C = nullptr; res = nullptr;
            M = g.M2; ldc = g.Nc2; co = 0;
        }
    }

    if constexpr (XSWZ) {
        if (!qrole) {
            int h = by * 4 + bx;               // gridDim.x == 4
            int lby = (h >> 5) * 8 + (h & 7);  // same-XCD ids share lby
            if (lby * BM >= M) return;         // guard padded rows
            by = lby;
            bx = (h >> 3) & 3;
        }
    }

    const int t = threadIdx.x;
    const int wave = t >> 6, lane = t & 63;
    const int q = lane >> 4, l16 = lane & 15;
    const int row0 = by * BM;
    const int col0 = bx * BN;
    const int wm = wave & 1, wn = wave >> 1;

    if constexpr (FILL) {
        if (!qrole && bx == 0 && t < BM) {
            int rg = row0 + t;
            if (rg < M) {
                int c = g.coli[rg];
                int p = atomicAdd(&g.cursor[c], 1);
                g.elist[p] = rg;
            }
        }
    }

    f32x4 acc[NP2][FM][FN];
    #pragma unroll
    for (int p2 = 0; p2 < NP2; p2++)
        #pragma unroll
        for (int i = 0; i < FM; i++)
            #pragma unroll
            for (int j = 0; j < FN; j++) acc[p2][i][j] = (f32x4){0.f, 0.f, 0.f, 0.f};

    for (int k0 = 0; k0 < K; k0 += BK) {
        #pragma unroll
        for (int p = 0; p < PA; p++) {
            int chunk = p * 256 + t;
            int r = chunk >> 3;
            int cs = (((chunk & 7) ^ (r & 7)) * 8);   // XOR bank swizzle
            int gr = row0 + r; if (gr >= M) gr = M - 1;
            const short* gsrc = A + (size_t)gr * K + k0 + cs;
            short* ldst = &As[(p * 256 + wave * 64) * 8];
            GL2LDS16(gsrc, ldst);
        }
        #pragma unroll
        for (int p2 = 0; p2 < NP2; p2++) {
            if (!(PAN2 && p2 == 1 && qrole)) {
                #pragma unroll
                for (int p = 0; p < PB; p++) {
                    int chunk = p * 256 + t;
                    int r = chunk >> 3;
                    int cs = (((chunk & 7) ^ (r & 7)) * 8);
                    const short* gsrc = Bt + (size_t)(col0 + p2 * 256 + r) * K + k0 + cs;
                    short* ldst = &Bs[p2 * BN * BK + (p * 256 + wave * 64) * 8];
                    GL2LDS16(gsrc, ldst);
                }
            }
        }
        __syncthreads();
        #pragma unroll
        for (int ks = 0; ks < 2; ks++) {
            short8 af[FM];
            #pragma unroll
            for (int mi = 0; mi < FM; mi++) {
                int R = wm * HM + mi * 16 + l16;
                int slot = ((ks * 4 + q) ^ (R & 7)) * 8;
                af[mi] = *(const short8*)&As[R * BK + slot];
            }
            #pragma unroll
            for (int p2 = 0; p2 < NP2; p2++) {
                if (!(PAN2 && p2 == 1 && qrole)) {
                    short8 bfr[FN];
                    #pragma unroll
                    for (int ni = 0; ni < FN; ni++) {
                        int R = wn * HN + ni * 16 + l16;
                        int slot = ((ks * 4 + q) ^ (R & 7)) * 8;
                        bfr[ni] = *(const short8*)&Bs[p2 * BN * BK + R * BK + slot];
                    }
                    #pragma unroll
                    for (int mi = 0; mi < FM; mi++)
                        #pragma unroll
                        for (int ni = 0; ni < FN; ni++)
                            acc[p2][mi][ni] = __builtin_amdgcn_mfma_f32_16x16x32_bf16(
                                af[mi], bfr[ni], acc[p2][mi][ni], 0, 0, 0);
                }
            }
        }
        __syncthreads();
    }

    // ---- epilogue; C/D layout: col = l16, row = q*4 + r ----
    #pragma unroll
    for (int p2 = 0; p2 < NP2; p2++) {
        if (PAN2 && p2 == 1 && qrole) continue;
        #pragma unroll
        for (int ni = 0; ni < FN; ni++) {
            int cg = col0 + p2 * 256 + wn * HN + ni * 16 + l16;
            float bv = bias[cg];
            if constexpr (EPI == 1) {
                float ga = g.gamma[cg], be = g.beta[cg];
                #pragma unroll
                for (int mi = 0; mi < FM; mi++) {
                    #pragma unroll
                    for (int r = 0; r < 4; r++) {
                        float v = acc[p2][mi][ni][r] + bv;
                        float s = v, sq = v * v;
                        s += __shfl_xor(s, 1, 64);  sq += __shfl_xor(sq, 1, 64);
                        s += __shfl_xor(s, 2, 64);  sq += __shfl_xor(sq, 2, 64);
                        s += __shfl_xor(s, 4, 64);  sq += __shfl_xor(sq, 4, 64);
                        float mean = s * 0.125f;
                        float var = sq * 0.125f - mean * mean;
                        float o = fmaxf((v - mean) * rsqrtf(var + 1e-5f) * ga + be, 0.f);
                        int rg = row0 + wm * HM + mi * 16 + q * 4 + r;
                        if (rg < M) Cbf[(size_t)rg * ldc + co + cg] = f2bf(o);
                    }
                }
            } else {
                #pragma unroll
                for (int mi = 0; mi < FM; mi++) {
                    #pragma unroll
                    for (int r = 0; r < 4; r++) {
                        int rg = row0 + wm * HM + mi * 16 + q * 4 + r;
                        if (rg < M) {
                            float v = acc[p2][mi][ni][r] + bv;
                            if (res) v += res[(size_t)rg * ldc + co + cg];
                            if (C)   C[(size_t)rg * ldc + co + cg] = v;
                            if (Cbf) Cbf[(size_t)rg * ldc + co + cg] = f2bf(v);
                        }
                    }
                }
                if constexpr (VB) {
                    bool vpanel = PAN2 ? (p2 == 1) : (!qrole && cg >= 256);
                    if (vpanel) {
                        float part = 0.f;
                        #pragma unroll
                        for (int mi = 0; mi < FM; mi++)
                            #pragma unroll
                            for (int r = 0; r < 4; r++) {
                                int rg = row0 + wm * HM + mi * 16 + q * 4 + r;
                                if (rg < M) part += acc[p2][mi][ni][r] + bv;
                            }
                        part += __shfl_xor(part, 16, 64);
                        part += __shfl_xor(part, 32, 64);
                        if (q == 0) atomicAdd(&g.vbar[cg - 256], part);
                    }
                }
            }
        }
    }
}

// ==================================================================== merged prep
// Roles: [0,NW) weight transpose (Wn1 only top half) | [NW,NW+NF) W2f fuse
// (16 blocks x 16 cols; LDS colv, broadcast inner loop — R17) | [.,+NP) x prep
// | rest counts-zero.
struct PrepPack {
    const float* wsrc[7];
    short* wdst[7];
    int wK[7];
    int wE[7];
    int wstart[7];
    int NW, NF, NP;
    const float* Wo; const float* Wn1s; const float* bo; const float* bn1;
    short* Wn1t; float* b2f;
    const float* x;
    short* x_bf;
    short* cat_bf;
    float2* xs;
    const float* gng;
    const float* gnb;
    float* vbar;
    const float* bk;
    const float* bv;
    float* bkv;
    int* counts;
    int N;
};

__global__ __launch_bounds__(256) void prep_kernel(PrepPack p)
{
    int bid = blockIdx.x;
    int t = threadIdx.x;
    if (bid < p.NW) {
        int m = 0;
        #pragma unroll
        for (int i = 1; i < 7; i++) if (bid >= p.wstart[i]) m = i;
        int k0 = (bid - p.wstart[m]) * 16;
        const float* src = p.wsrc[m];
        short16 o;
        #pragma unroll
        for (int j = 0; j < 16; j++) o[j] = f2bf(src[(size_t)(k0 + j) * 256 + t]);
        *(short16*)(p.wdst[m] + (size_t)t * p.wK[m] + k0) = o;
        return;
    }
    if (bid < p.NW + p.NF) {
        // R17 W2f fuse: block handles 16 output cols c0..c0+15.
        // W2f[k][c] = sum_j Wo[k][j] * Wn1[256+j][c];  thread k = t.
        int c0 = (bid - p.NW) * 16;
        __shared__ float colv[16][257];
        __shared__ float red2[16][17];
        // coalesced colv load: 16 threads (same j) read 16 consecutive c
        #pragma unroll
        for (int i = 0; i < 16; i++) {
            int j = (t >> 4) + i * 16;
            colv[t & 15][j] = p.Wn1s[(size_t)(256 + j) * 256 + c0 + (t & 15)];
        }
        __syncthreads();
        float acc16[16];
        #pragma unroll
        for (int c = 0; c < 16; c++) acc16[c] = 0.f;
        const float* wrow = p.Wo + (size_t)t * 256;
        for (int j = 0; j < 256; j += 4) {
            float4 wv = *(const float4*)&wrow[j];    // amortized 16x across cols
            #pragma unroll
            for (int c = 0; c < 16; c++) {           // colv reads: lane-broadcast
                acc16[c] += wv.x * colv[c][j]     + wv.y * colv[c][j + 1]
                          + wv.z * colv[c][j + 2] + wv.w * colv[c][j + 3];
            }
        }
        #pragma unroll
        for (int c = 0; c < 16; c++)
            p.Wn1t[(size_t)(c0 + c) * 512 + 256 + t] = f2bf(acc16[c]);
        // b2f[c] = bn1[c] + sum_j bo[j]*colv[c][j]; 16 j-slices per col
        int c = t & 15, js = t >> 4;
        float pb2 = 0.f;
        for (int j = js; j < 256; j += 16) pb2 += p.bo[j] * colv[c][j];
        red2[c][js] = pb2;
        __syncthreads();
        if (t < 16) {
            float s = 0.f;
            #pragma unroll
            for (int i = 0; i < 16; i++) s += red2[t][i];
            p.b2f[c0 + t] = p.bn1[c0 + t] + s;
        }
        return;
    }
    if (bid >= p.NW + p.NF + p.NP) {
        int i = (bid - p.NW - p.NF - p.NP) * 256 + t;
        if (i < p.N) p.counts[i] = 0;
        return;
    }
    int pb = bid - p.NW - p.NF;
    if (pb == 0) {
        p.vbar[t] = 0.f;
        p.bkv[t] = p.bk[t];
        p.bkv[256 + t] = p.bv[t];
    }
    int r = pb * 8 + (t >> 5);
    int g = t & 31;
    if (r >= p.N) return;
    size_t xb = (size_t)r * CH + g * 8;
    float4 a = *(const float4*)&p.x[xb];
    float4 b = *(const float4*)&p.x[xb + 4];
    short8 xr;
    xr[0] = f2bf(a.x); xr[1] = f2bf(a.y); xr[2] = f2bf(a.z); xr[3] = f2bf(a.w);
    xr[4] = f2bf(b.x); xr[5] = f2bf(b.y); xr[6] = f2bf(b.z); xr[7] = f2bf(b.w);
    *(short8*)&p.x_bf[xb] = xr;
    float s  = a.x + a.y + a.z + a.w + b.x + b.y + b.z + b.w;
    float s2 = a.x*a.x + a.y*a.y + a.z*a.z + a.w*a.w
             + b.x*b.x + b.y*b.y + b.z*b.z + b.w*b.w;
    p.xs[(size_t)r * 32 + g] = make_float2(s, s2);
    float m = s * 0.125f;
    float var = s2 * 0.125f - m * m;
    float rsd = rsqrtf(var + 1e-5f);
    float4 g0 = *(const float4*)&p.gng[g * 8];
    float4 g1 = *(const float4*)&p.gng[g * 8 + 4];
    float4 b0 = *(const float4*)&p.gnb[g * 8];
    float4 b1 = *(const float4*)&p.gnb[g * 8 + 4];
    short8 o;
    o[0] = f2bf(fmaxf((a.x - m) * rsd * g0.x + b0.x, 0.f));
    o[1] = f2bf(fmaxf((a.y - m) * rsd * g0.y + b0.y, 0.f));
    o[2] = f2bf(fmaxf((a.z - m) * rsd * g0.z + b0.z, 0.f));
    o[3] = f2bf(fmaxf((a.w - m) * rsd * g0.w + b0.w, 0.f));
    o[4] = f2bf(fmaxf((b.x - m) * rsd * g1.x + b1.x, 0.f));
    o[5] = f2bf(fmaxf((b.y - m) * rsd * g1.y + b1.y, 0.f));
    o[6] = f2bf(fmaxf((b.z - m) * rsd * g1.z + b1.z, 0.f));
    o[7] = f2bf(fmaxf((b.w - m) * rsd * g1.w + b1.w, 0.f));
    *(short8*)&p.cat_bf[(size_t)r * (2 * CH) + g * 8] = o;
}

// ==================================================================== edge stats
// R13: computes group stats AND materializes the full normalized edge-MLP
// input e1n[E][768] = bf16(relu(gn_g24(cat(x[row], x[col], eattr)))) once.
__global__ __launch_bounds__(256) void estats_kernel(
    const float* __restrict__ eattr, const int* __restrict__ rowi,
    const int* __restrict__ coli, const float2* __restrict__ xs,
    const short* __restrict__ x_bf,
    const float* __restrict__ g1v, const float* __restrict__ b1v,
    short* __restrict__ e1n, int* __restrict__ counts, int E)
{
    __shared__ float2 ea[8][32];
    __shared__ float2 musr[8][32];
    int t = threadIdx.x;
    int slot = t >> 5, g = t & 31;
    int e = blockIdx.x * 8 + slot;
    float4 a = *(const float4*)&eattr[(size_t)e * CH + g * 8];
    float4 b = *(const float4*)&eattr[(size_t)e * CH + g * 8 + 4];
    float s  = a.x + a.y + a.z + a.w + b.x + b.y + b.z + b.w;
    float s2 = a.x*a.x + a.y*a.y + a.z*a.z + a.w*a.w
             + b.x*b.x + b.y*b.y + b.z*b.z + b.w*b.w;
    ea[slot][g] = make_float2(s, s2);
    int r = rowi[e], c = coli[e];
    if (g == 0) atomicAdd(&counts[c], 1);
    __syncthreads();
    float S = 0.f, S2 = 0.f;
    #pragma unroll
    for (int j = 0; j < 3; j++) {
        int b3 = 3 * g + j;
        int src = b3 >> 5, idx = b3 & 31;
        float2 v;
        if (src == 0)      v = xs[(size_t)r * 32 + idx];
        else if (src == 1) v = xs[(size_t)c * 32 + idx];
        else               v = ea[slot][idx];
        S += v.x; S2 += v.y;
    }
    float m = S * (1.f / 24.f);
    float var = S2 * (1.f / 24.f) - m * m;
    musr[slot][g] = make_float2(m, rsqrtf(var + 1e-5f));
    __syncthreads();
    // normalize all 3 segments; 8-chunks never cross a group of 24
    #pragma unroll
    for (int seg = 0; seg < 3; seg++) {
        int pos = seg * 256 + g * 8;
        float2 ms = musr[slot][pos / 24];
        float4 ga  = *(const float4*)&g1v[pos];
        float4 ga2 = *(const float4*)&g1v[pos + 4];
        float4 gb  = *(const float4*)&b1v[pos];
        float4 gb2 = *(const float4*)&b1v[pos + 4];
        float v0, v1, v2, v3, v4, v5, v6, v7;
        if (seg == 2) {
            v0 = a.x; v1 = a.y; v2 = a.z; v3 = a.w;
            v4 = b.x; v5 = b.y; v6 = b.z; v7 = b.w;
        } else {
            const short* srow = x_bf + (size_t)(seg == 0 ? r : c) * CH + g * 8;
            short8 v8 = *(const short8*)srow;
            v0 = bf2f(v8[0]); v1 = bf2f(v8[1]); v2 = bf2f(v8[2]); v3 = bf2f(v8[3]);
            v4 = bf2f(v8[4]); v5 = bf2f(v8[5]); v6 = bf2f(v8[6]); v7 = bf2f(v8[7]);
        }
        short8 o;
        o[0] = f2bf(fmaxf((v0 - ms.x) * ms.y * ga.x  + gb.x,  0.f));
        o[1] = f2bf(fmaxf((v1 - ms.x) * ms.y * ga.y  + gb.y,  0.f));
        o[2] = f2bf(fmaxf((v2 - ms.x) * ms.y * ga.z  + gb.z,  0.f));
        o[3] = f2bf(fmaxf((v3 - ms.x) * ms.y * ga.w  + gb.w,  0.f));
        o[4] = f2bf(fmaxf((v4 - ms.x) * ms.y * ga2.x + gb2.x, 0.f));
        o[5] = f2bf(fmaxf((v5 - ms.x) * ms.y * ga2.y + gb2.y, 0.f));
        o[6] = f2bf(fmaxf((v6 - ms.x) * ms.y * ga2.z + gb2.z, 0.f));
        o[7] = f2bf(fmaxf((v7 - ms.x) * ms.y * ga2.w + gb2.w, 0.f));
        *(short8*)&e1n[(size_t)e * 768 + pos] = o;
    }
}

// ==================================================================== attention
// block = node; fused scoring (all 4 waves cooperate) + per-wave (=head)
// online softmax + PV. R16: writes straight into cat_bf right half
// (row stride 512) — feeds fused MLP1 without the Wo stage.
__global__ __launch_bounds__(256) void attn_kernel(
    const short* __restrict__ qb, const short* __restrict__ kvb,
    const int* __restrict__ offsets, const int* __restrict__ elist,
    const float* __restrict__ vbar, short* __restrict__ gout, int N, int E)
{
    __shared__ int eidx[64];
    __shared__ float scl[4 * 64];
    int n = blockIdx.x;
    int wave = threadIdx.x >> 6;
    int lane = threadIdx.x & 63;
    int s0 = offsets[n], s1 = offsets[n + 1];
    float q0 = bf2f(qb[(size_t)n * CH + lane]);
    float q1 = bf2f(qb[(size_t)n * CH + 64 + lane]);
    float q2 = bf2f(qb[(size_t)n * CH + 128 + lane]);
    float q3 = bf2f(qb[(size_t)n * CH + 192 + lane]);
    float out = 0.f, m = -INFINITY, l = 0.f;
    for (int base = s0; base < s1; base += 64) {
        int cn = s1 - base; if (cn > 64) cn = 64;
        if (wave == 0 && lane < cn) eidx[lane] = elist[base + lane];
        __syncthreads();
        for (int j = wave; j < cn; j += 4) {
            int e = eidx[j];
            const short* kr = kvb + (size_t)e * 512;
            float d0 = warp_sum64(q0 * bf2f(kr[lane]));
            float d1 = warp_sum64(q1 * bf2f(kr[64 + lane]));
            float d2 = warp_sum64(q2 * bf2f(kr[128 + lane]));
            float d3 = warp_sum64(q3 * bf2f(kr[192 + lane]));
            if (lane == 0) {
                scl[j]       = d0 * 0.125f;   // 1/sqrt(64)
                scl[64 + j]  = d1 * 0.125f;
                scl[128 + j] = d2 * 0.125f;
                scl[192 + j] = d3 * 0.125f;
            }
        }
        __syncthreads();
        float s = (lane < cn) ? scl[wave * 64 + lane] : -INFINITY;
        float mc = warp_max64(s);
        float nm = fmaxf(m, mc);
        float scale = __expf(m - nm);
        float pp = (lane < cn) ? __expf(s - nm) : 0.f;
        float ps = warp_sum64(pp);
        l = l * scale + ps;
        out *= scale;
        m = nm;
        for (int i = 0; i < cn; i++) {
            float pi = __shfl(pp, i, 64);
            int ei = eidx[i];
            out += pi * bf2f(kvb[(size_t)ei * 512 + 256 + wave * 64 + lane]);
        }
        __syncthreads();   // protect eidx/scl before next chunk
    }
    float res;
    if (s1 > s0) res = out / l;
    else         res = vbar[wave * 64 + lane] * (1.f / (float)E);  // uniform over all E
    gout[(size_t)n * 512 + wave * 64 + lane] = f2bf(res);
}

// ==================================================================== launch
extern "C" void kernel_launch(void* const* d_in, const int* in_sizes, int n_in,
                              void* d_out, int out_size, void* d_ws, size_t ws_size,
                              hipStream_t stream)
{
    const float* x       = (const float*)d_in[0];
    const int*   ei      = (const int*)d_in[1];
    const float* eattr   = (const float*)d_in[2];
    const float* gn_e1_g = (const float*)d_in[3];
    const float* gn_e1_b = (const float*)d_in[4];
    const float* We1     = (const float*)d_in[5];
    const float* be1     = (const float*)d_in[6];
    const float* gn_e2_g = (const float*)d_in[7];
    const float* gn_e2_b = (const float*)d_in[8];
    const float* We2     = (const float*)d_in[9];
    const float* be2     = (const float*)d_in[10];
    const float* gn_n_g  = (const float*)d_in[11];
    const float* gn_n_b  = (const float*)d_in[12];
    const float* Wq      = (const float*)d_in[13];
    const float* bq      = (const float*)d_in[14];
    const float* Wk      = (const float*)d_in[15];
    const float* bk      = (const float*)d_in[16];
    const float* Wv      = (const float*)d_in[17];
    const float* bv      = (const float*)d_in[18];
    const float* Wo      = (const float*)d_in[19];
    const float* bo      = (const float*)d_in[20];
    const float* Wn1     = (const float*)d_in[21];
    const float* bn1     = (const float*)d_in[22];
    const float* gn_n2_g = (const float*)d_in[23];
    const float* gn_n2_b = (const float*)d_in[24];
    const float* Wn2     = (const float*)d_in[25];
    const float* bn2     = (const float*)d_in[26];

    const int N = in_sizes[0] / CH;
    const int E = in_sizes[2] / CH;

    float* nout = (float*)d_out;
    float* eout = (float*)d_out + (size_t)N * CH;

    // ---- workspace ----
    char* base = (char*)d_ws;
    short* kv_bf  = (short*)base; base += (size_t)E * 512 * 2;
    short* h2_bf  = (short*)base; base += (size_t)E * CH * 2;
    short* eo_bf  = (short*)base; base += (size_t)E * CH * 2;
    short* e1n    = (short*)base; base += (size_t)E * 768 * 2;
    short* q_bf   = (short*)base; base += (size_t)N * CH * 2;
    short* g_bf   = (short*)base; base += (size_t)N * CH * 2;  // unused (layout kept)
    short* cat_bf = (short*)base; base += (size_t)N * 2 * CH * 2;
    short* hn_bf  = (short*)base; base += (size_t)N * CH * 2;
    short* x_bf   = (short*)base; base += (size_t)N * CH * 2;
    float2* xs    = (float2*)base; base += (size_t)N * 32 * 8;
    float* vbar   = (float*)base; base += 1024;
    float* bkv    = (float*)base; base += 2048;
    float* b2f    = (float*)base; base += 1024;
    short* We1t = (short*)base; base += (size_t)768 * 256 * 2;
    short* We2t = (short*)base; base += (size_t)256 * 256 * 2;
    short* Wqt  = (short*)base; base += (size_t)256 * 256 * 2;
    short* Wkvt = (short*)base; base += (size_t)512 * 256 * 2;
    short* Wn1t = (short*)base; base += (size_t)512 * 256 * 2;
    short* Wn2t = (short*)base; base += (size_t)256 * 256 * 2;
    int* counts  = (int*)base;
    int* offsets = counts + N;
    int* cursor  = offsets + (N + 1) + 3;
    int* elist   = cursor + N;

    const int* rowi = ei;
    const int* coli = ei + E;
    (void)g_bf;

    dim3 blk(256);

    // ---- merged prep (weights, W2f fuse, x, counts) ----
    PrepPack pp;
    const float* wsrc[7] = {We1, We2, Wq, Wk, Wv, Wn1, Wn2};
    short* wdst[7] = {We1t, We2t, Wqt, Wkvt, Wkvt + (size_t)256 * 256, Wn1t, Wn2t};
    const int wKd[7] = {768, 256, 256, 256, 256, 512, 256};
    const int wEd[7] = {768, 256, 256, 256, 256, 256, 256};  // Wn1: top half only
    int acc = 0;
    for (int i = 0; i < 7; i++) {
        pp.wsrc[i] = wsrc[i]; pp.wdst[i] = wdst[i];
        pp.wK[i] = wKd[i]; pp.wE[i] = wEd[i];
        pp.wstart[i] = acc; acc += wEd[i] / 16;
    }
    pp.NW = acc;
    pp.NF = 16;
    pp.NP = (N + 7) / 8;
    pp.Wo = Wo; pp.Wn1s = Wn1; pp.bo = bo; pp.bn1 = bn1;
    pp.Wn1t = Wn1t; pp.b2f = b2f;
    pp.x = x; pp.x_bf = x_bf; pp.cat_bf = cat_bf; pp.xs = xs;
    pp.gng = gn_n_g; pp.gnb = gn_n_b;
    pp.vbar = vbar; pp.bk = bk; pp.bv = bv; pp.bkv = bkv;
    pp.counts = counts; pp.N = N;
    int nzero = (N + 255) / 256;
    prep_kernel<<<pp.NW + pp.NF + pp.NP + nzero, blk, 0, stream>>>(pp);

    estats_kernel<<<E / 8, blk, 0, stream>>>(eattr, rowi, coli, xs, x_bf,
                                             gn_e1_g, gn_e1_b, e1n, counts, E);

    GArgs ga = {};
    // ---- GEMM1: plain GEMM on e1n, K=768, XCD swizzle, +concurrent scan ----
    ga.A = e1n; ga.Bt = We1t; ga.bias = be1; ga.Cbf = h2_bf;
    ga.gamma = gn_e2_g; ga.beta = gn_e2_b;
    ga.M = E; ga.K = 3 * CH; ga.Nc = CH; ga.ldc = CH; ga.coff = 0;
    ga.counts = counts; ga.offsets = offsets; ga.cursor = cursor; ga.Nn = N;
    mfma_gemm<64, 64, 1, 0, 0, 0, 1, 0, 1><<<dim3(4, 257), blk, 0, stream>>>(ga);

    // ---- GEMM2: eout (f32, +eattr residual) + eo_bf, XCD swizzle ----
    ga = {};
    ga.A = h2_bf; ga.Bt = We2t; ga.bias = be2; ga.res = eattr;
    ga.C = eout; ga.Cbf = eo_bf;
    ga.M = E; ga.K = CH; ga.Nc = CH; ga.ldc = CH; ga.coff = 0;
    mfma_gemm<64, 64, 0, 0, 0, 0, 0, 0, 1><<<dim3(4, 256), blk, 0, stream>>>(ga);

    // ---- fused KV (2-panel, vbar, CSR fill, XCD swizzle) + Q in one launch ----
    ga = {};
    ga.A = eo_bf; ga.Bt = Wkvt; ga.bias = bkv; ga.Cbf = kv_bf; ga.vbar = vbar;
    ga.M = E; ga.K = CH; ga.Nc = 512; ga.ldc = 512; ga.coff = 0;
    ga.A2 = x_bf; ga.Bt2 = Wqt; ga.bias2 = bq; ga.Cbf2 = q_bf;
    ga.M2 = N; ga.Nc2 = CH; ga.y_split = 256;
    ga.coli = coli; ga.cursor = cursor; ga.elist = elist;
    mfma_gemm<64, 64, 0, 1, 1, 1, 0, 1, 1><<<dim3(4, 256 + (N + 63) / 64), blk, 0, stream>>>(ga);

    // ---- attention -> cat right half directly (Wo folded into MLP1) ----
    attn_kernel<<<N, blk, 0, stream>>>(q_bf, kv_bf, offsets, elist, vbar,
                                       cat_bf + 256, N, E);

    // ---- node MLP1 (fused weights: [Wn1_top; Wo@Wn1_bot], bias b2f) ----
    ga = {};
    ga.A = cat_bf; ga.Bt = Wn1t; ga.bias = b2f; ga.Cbf = hn_bf;
    ga.gamma = gn_n2_g; ga.beta = gn_n2_b;
    ga.M = N; ga.K = 2 * CH; ga.Nc = CH; ga.ldc = CH; ga.coff = 0;
    mfma_gemm<32, 64, 1, 0, 0, 0><<<dim3(4, (N + 31) / 32), blk, 0, stream>>>(ga);

    // ---- node MLP2 (+x residual, f32 out) ----
    ga = {};
    ga.A = hn_bf; ga.Bt = Wn2t; ga.bias = bn2; ga.res = x; ga.C = nout;
    ga.M = N; ga.K = CH; ga.Nc = CH; ga.ldc = CH; ga.coff = 0;
    mfma_gemm<32, 64, 0, 0, 0, 0><<<dim3(4, (N + 31) / 32), blk, 0, stream>>>(ga);
}

// Round 10
// 229.785 us; speedup vs baseline: 1.1281x; 1.1281x over previous
//
#include <hip/hip_runtime.h>
#include <hip/hip_bf16.h>
#include <stdint.h>
#include <math.h>

#define CH 256

typedef __attribute__((ext_vector_type(8)))  short short8;
typedef __attribute__((ext_vector_type(16))) short short16;
typedef __attribute__((ext_vector_type(4)))  float f32x4;

#define GL2LDS16(g, l) __builtin_amdgcn_global_load_lds(                       \
    (const __attribute__((address_space(1))) void*)(g),                        \
    (__attribute__((address_space(3))) void*)(l), 16, 0, 0)

__device__ inline short f2bf(float f) {
    __hip_bfloat16 h = __float2bfloat16(f);
    short s;
    __builtin_memcpy(&s, &h, 2);
    return s;
}

__device__ inline float bf2f(short s) {
    unsigned u = ((unsigned)(unsigned short)s) << 16;
    float f;
    __builtin_memcpy(&f, &u, 4);
    return f;
}

__device__ inline float warp_sum64(float v) {
    v += __shfl_xor(v, 32, 64);
    v += __shfl_xor(v, 16, 64);
    v += __shfl_xor(v, 8, 64);
    v += __shfl_xor(v, 4, 64);
    v += __shfl_xor(v, 2, 64);
    v += __shfl_xor(v, 1, 64);
    return v;
}

__device__ inline float warp_max64(float v) {
    v = fmaxf(v, __shfl_xor(v, 32, 64));
    v = fmaxf(v, __shfl_xor(v, 16, 64));
    v = fmaxf(v, __shfl_xor(v, 8, 64));
    v = fmaxf(v, __shfl_xor(v, 4, 64));
    v = fmaxf(v, __shfl_xor(v, 2, 64));
    v = fmaxf(v, __shfl_xor(v, 1, 64));
    return v;
}

// ==================================================================== MFMA GEMM
// BMxBN tile, BK=64, 2x2 wave grid, 16x16x32 bf16 MFMA. Single-buffer
// 2-barrier K-loop (R12 dbuf regressed; implicit wave overlap suffices).
// R16: Wo GEMM folded into MLP1 via precomputed W2f = Wo @ Wn1_bot.
// R18: W2f fuse moved into estats (65 parallel blocks, coalesced row loop)
//      — R17's in-prep serial fuse (44.5us, 1.6% occupancy) was the bug.
// EPI 1: GroupNorm(8 cols)+ReLU -> bf16 Cbf only. EPI 0: f32 C/res/bf16 Cbf.
// DUAL : blocks with by >= y_split run the Q GEMM (A2/Bt2/bias2/Cbf2).
// VB   : V-panel column sums atomically into vbar (KV path).
// FILL : edge-role blocks with logical bx==0 scatter rows into elist.
// SCAN : extra grid row runs the CSR prefix scan concurrently. [R11]
// PAN2 : block computes TWO output panels (cols c, c+256) per A staging. [R11]
// XSWZ : XCD-aware remap — ids {h,h+8,h+16,h+24} (same XCD under round-robin)
//        share logical row-panel lby -> A re-reads are L2 hits. [R14]
struct GArgs {
    const short* A; const short* Bt; const float* bias; const float* res;
    float* C; short* Cbf;
    const float* gamma; const float* beta; float* vbar;
    int M, K, Nc, ldc, coff;
    const short* A2; const short* Bt2; const float* bias2; short* Cbf2;
    int M2, Nc2, y_split;
    const int* coli;
    int* cursor; int* elist;
    const int* counts; int* offsets; int Nn;   // SCAN role
};

template <int BM, int BN, int EPI, int DUAL, int VB, int FILL,
          int SCAN = 0, int PAN2 = 0, int XSWZ = 0>
__global__ __launch_bounds__(256) void mfma_gemm(GArgs g)
{
    constexpr int BK = 64;
    constexpr int HM = BM / 2, HN = BN / 2;
    constexpr int FM = HM / 16, FN = HN / 16;
    constexpr int PA = BM / 32;
    constexpr int PB = BN / 32;
    constexpr int NP2 = PAN2 ? 2 : 1;
    __shared__ short As[BM * BK];
    __shared__ short Bs[NP2 * BN * BK];

    const short* A = g.A; const short* Bt = g.Bt;
    const float* bias = g.bias; const float* res = g.res;
    float* C = g.C; short* Cbf = g.Cbf;
    int M = g.M, ldc = g.ldc, co = g.coff;
    const int K = g.K;
    int by = blockIdx.y, bx = blockIdx.x;

    if constexpr (SCAN) {
        if (by == (int)gridDim.y - 1) {
            const int t0 = threadIdx.x;
            if (bx == 0) {
                int* ss = (int*)As;
                int base8 = t0 * 8;
                int loc[8]; int srun = 0;
                #pragma unroll
                for (int j = 0; j < 8; j++) {
                    int idx = base8 + j;
                    int c = (idx < g.Nn) ? g.counts[idx] : 0;
                    loc[j] = srun; srun += c;
                }
                ss[t0] = srun;
                __syncthreads();
                for (int off = 1; off < 256; off <<= 1) {
                    int v = (t0 >= off) ? ss[t0 - off] : 0;
                    __syncthreads();
                    ss[t0] += v;
                    __syncthreads();
                }
                int excl = (t0 > 0) ? ss[t0 - 1] : 0;
                #pragma unroll
                for (int j = 0; j < 8; j++) {
                    int idx = base8 + j;
                    if (idx < g.Nn) {
                        int v = excl + loc[j];
                        g.offsets[idx] = v;
                        g.cursor[idx]  = v;
                    }
                }
                if (t0 == 255) g.offsets[g.Nn] = ss[255];
            }
            return;
        }
    }

    bool qrole = false;
    if constexpr (DUAL) {
        if (by >= g.y_split) {
            by -= g.y_split;
            if (bx * BN >= g.Nc2) return;
            qrole = true;
            A = g.A2; Bt = g.Bt2; bias = g.bias2; Cbf = g.Cbf2;
            C = nullptr; res = nullptr;
            M = g.M2; ldc = g.Nc2; co = 0;
        }
    }

    if constexpr (XSWZ) {
        if (!qrole) {
            int h = by * 4 + bx;               // gridDim.x == 4
            int lby = (h >> 5) * 8 + (h & 7);  // same-XCD ids share lby
            if (lby * BM >= M) return;         // guard padded rows
            by = lby;
            bx = (h >> 3) & 3;
        }
    }

    const int t = threadIdx.x;
    const int wave = t >> 6, lane = t & 63;
    const int q = lane >> 4, l16 = lane & 15;
    const int row0 = by * BM;
    const int col0 = bx * BN;
    const int wm = wave & 1, wn = wave >> 1;

    if constexpr (FILL) {
        if (!qrole && bx == 0 && t < BM) {
            int rg = row0 + t;
            if (rg < M) {
                int c = g.coli[rg];
                int p = atomicAdd(&g.cursor[c], 1);
                g.elist[p] = rg;
            }
        }
    }

    f32x4 acc[NP2][FM][FN];
    #pragma unroll
    for (int p2 = 0; p2 < NP2; p2++)
        #pragma unroll
        for (int i = 0; i < FM; i++)
            #pragma unroll
            for (int j = 0; j < FN; j++) acc[p2][i][j] = (f32x4){0.f, 0.f, 0.f, 0.f};

    for (int k0 = 0; k0 < K; k0 += BK) {
        #pragma unroll
        for (int p = 0; p < PA; p++) {
            int chunk = p * 256 + t;
            int r = chunk >> 3;
            int cs = (((chunk & 7) ^ (r & 7)) * 8);   // XOR bank swizzle
            int gr = row0 + r; if (gr >= M) gr = M - 1;
            const short* gsrc = A + (size_t)gr * K + k0 + cs;
            short* ldst = &As[(p * 256 + wave * 64) * 8];
            GL2LDS16(gsrc, ldst);
        }
        #pragma unroll
        for (int p2 = 0; p2 < NP2; p2++) {
            if (!(PAN2 && p2 == 1 && qrole)) {
                #pragma unroll
                for (int p = 0; p < PB; p++) {
                    int chunk = p * 256 + t;
                    int r = chunk >> 3;
                    int cs = (((chunk & 7) ^ (r & 7)) * 8);
                    const short* gsrc = Bt + (size_t)(col0 + p2 * 256 + r) * K + k0 + cs;
                    short* ldst = &Bs[p2 * BN * BK + (p * 256 + wave * 64) * 8];
                    GL2LDS16(gsrc, ldst);
                }
            }
        }
        __syncthreads();
        #pragma unroll
        for (int ks = 0; ks < 2; ks++) {
            short8 af[FM];
            #pragma unroll
            for (int mi = 0; mi < FM; mi++) {
                int R = wm * HM + mi * 16 + l16;
                int slot = ((ks * 4 + q) ^ (R & 7)) * 8;
                af[mi] = *(const short8*)&As[R * BK + slot];
            }
            #pragma unroll
            for (int p2 = 0; p2 < NP2; p2++) {
                if (!(PAN2 && p2 == 1 && qrole)) {
                    short8 bfr[FN];
                    #pragma unroll
                    for (int ni = 0; ni < FN; ni++) {
                        int R = wn * HN + ni * 16 + l16;
                        int slot = ((ks * 4 + q) ^ (R & 7)) * 8;
                        bfr[ni] = *(const short8*)&Bs[p2 * BN * BK + R * BK + slot];
                    }
                    #pragma unroll
                    for (int mi = 0; mi < FM; mi++)
                        #pragma unroll
                        for (int ni = 0; ni < FN; ni++)
                            acc[p2][mi][ni] = __builtin_amdgcn_mfma_f32_16x16x32_bf16(
                                af[mi], bfr[ni], acc[p2][mi][ni], 0, 0, 0);
                }
            }
        }
        __syncthreads();
    }

    // ---- epilogue; C/D layout: col = l16, row = q*4 + r ----
    #pragma unroll
    for (int p2 = 0; p2 < NP2; p2++) {
        if (PAN2 && p2 == 1 && qrole) continue;
        #pragma unroll
        for (int ni = 0; ni < FN; ni++) {
            int cg = col0 + p2 * 256 + wn * HN + ni * 16 + l16;
            float bv = bias[cg];
            if constexpr (EPI == 1) {
                float ga = g.gamma[cg], be = g.beta[cg];
                #pragma unroll
                for (int mi = 0; mi < FM; mi++) {
                    #pragma unroll
                    for (int r = 0; r < 4; r++) {
                        float v = acc[p2][mi][ni][r] + bv;
                        float s = v, sq = v * v;
                        s += __shfl_xor(s, 1, 64);  sq += __shfl_xor(sq, 1, 64);
                        s += __shfl_xor(s, 2, 64);  sq += __shfl_xor(sq, 2, 64);
                        s += __shfl_xor(s, 4, 64);  sq += __shfl_xor(sq, 4, 64);
                        float mean = s * 0.125f;
                        float var = sq * 0.125f - mean * mean;
                        float o = fmaxf((v - mean) * rsqrtf(var + 1e-5f) * ga + be, 0.f);
                        int rg = row0 + wm * HM + mi * 16 + q * 4 + r;
                        if (rg < M) Cbf[(size_t)rg * ldc + co + cg] = f2bf(o);
                    }
                }
            } else {
                #pragma unroll
                for (int mi = 0; mi < FM; mi++) {
                    #pragma unroll
                    for (int r = 0; r < 4; r++) {
                        int rg = row0 + wm * HM + mi * 16 + q * 4 + r;
                        if (rg < M) {
                            float v = acc[p2][mi][ni][r] + bv;
                            if (res) v += res[(size_t)rg * ldc + co + cg];
                            if (C)   C[(size_t)rg * ldc + co + cg] = v;
                            if (Cbf) Cbf[(size_t)rg * ldc + co + cg] = f2bf(v);
                        }
                    }
                }
                if constexpr (VB) {
                    bool vpanel = PAN2 ? (p2 == 1) : (!qrole && cg >= 256);
                    if (vpanel) {
                        float part = 0.f;
                        #pragma unroll
                        for (int mi = 0; mi < FM; mi++)
                            #pragma unroll
                            for (int r = 0; r < 4; r++) {
                                int rg = row0 + wm * HM + mi * 16 + q * 4 + r;
                                if (rg < M) part += acc[p2][mi][ni][r] + bv;
                            }
                        part += __shfl_xor(part, 16, 64);
                        part += __shfl_xor(part, 32, 64);
                        if (q == 0) atomicAdd(&g.vbar[cg - 256], part);
                    }
                }
            }
        }
    }
}

// ==================================================================== merged prep
// Roles: [0,NW) weight transpose (Wn1 top half only) | [NW,NW+NP) x prep
// | rest counts-zero. (W2f fuse moved to estats — R18.)
struct PrepPack {
    const float* wsrc[7];
    short* wdst[7];
    int wK[7];
    int wstart[7];
    int NW, NP;
    const float* x;
    short* x_bf;
    short* cat_bf;
    float2* xs;
    const float* gng;
    const float* gnb;
    float* vbar;
    const float* bk;
    const float* bv;
    float* bkv;
    int* counts;
    int N;
};

__global__ __launch_bounds__(256) void prep_kernel(PrepPack p)
{
    int bid = blockIdx.x;
    int t = threadIdx.x;
    if (bid < p.NW) {
        int m = 0;
        #pragma unroll
        for (int i = 1; i < 7; i++) if (bid >= p.wstart[i]) m = i;
        int k0 = (bid - p.wstart[m]) * 16;
        const float* src = p.wsrc[m];
        short16 o;
        #pragma unroll
        for (int j = 0; j < 16; j++) o[j] = f2bf(src[(size_t)(k0 + j) * 256 + t]);
        *(short16*)(p.wdst[m] + (size_t)t * p.wK[m] + k0) = o;
        return;
    }
    if (bid >= p.NW + p.NP) {
        int i = (bid - p.NW - p.NP) * 256 + t;
        if (i < p.N) p.counts[i] = 0;
        return;
    }
    int pb = bid - p.NW;
    if (pb == 0) {
        p.vbar[t] = 0.f;
        p.bkv[t] = p.bk[t];
        p.bkv[256 + t] = p.bv[t];
    }
    int r = pb * 8 + (t >> 5);
    int g = t & 31;
    if (r >= p.N) return;
    size_t xb = (size_t)r * CH + g * 8;
    float4 a = *(const float4*)&p.x[xb];
    float4 b = *(const float4*)&p.x[xb + 4];
    short8 xr;
    xr[0] = f2bf(a.x); xr[1] = f2bf(a.y); xr[2] = f2bf(a.z); xr[3] = f2bf(a.w);
    xr[4] = f2bf(b.x); xr[5] = f2bf(b.y); xr[6] = f2bf(b.z); xr[7] = f2bf(b.w);
    *(short8*)&p.x_bf[xb] = xr;
    float s  = a.x + a.y + a.z + a.w + b.x + b.y + b.z + b.w;
    float s2 = a.x*a.x + a.y*a.y + a.z*a.z + a.w*a.w
             + b.x*b.x + b.y*b.y + b.z*b.z + b.w*b.w;
    p.xs[(size_t)r * 32 + g] = make_float2(s, s2);
    float m = s * 0.125f;
    float var = s2 * 0.125f - m * m;
    float rsd = rsqrtf(var + 1e-5f);
    float4 g0 = *(const float4*)&p.gng[g * 8];
    float4 g1 = *(const float4*)&p.gng[g * 8 + 4];
    float4 b0 = *(const float4*)&p.gnb[g * 8];
    float4 b1 = *(const float4*)&p.gnb[g * 8 + 4];
    short8 o;
    o[0] = f2bf(fmaxf((a.x - m) * rsd * g0.x + b0.x, 0.f));
    o[1] = f2bf(fmaxf((a.y - m) * rsd * g0.y + b0.y, 0.f));
    o[2] = f2bf(fmaxf((a.z - m) * rsd * g0.z + b0.z, 0.f));
    o[3] = f2bf(fmaxf((a.w - m) * rsd * g0.w + b0.w, 0.f));
    o[4] = f2bf(fmaxf((b.x - m) * rsd * g1.x + b1.x, 0.f));
    o[5] = f2bf(fmaxf((b.y - m) * rsd * g1.y + b1.y, 0.f));
    o[6] = f2bf(fmaxf((b.z - m) * rsd * g1.z + b1.z, 0.f));
    o[7] = f2bf(fmaxf((b.w - m) * rsd * g1.w + b1.w, 0.f));
    *(short8*)&p.cat_bf[(size_t)r * (2 * CH) + g * 8] = o;
}

// ==================================================================== edge stats
// R13: computes group stats AND materializes the full normalized edge-MLP
// input e1n[E][768] = bf16(relu(gn_g24(cat(x[row], x[col], eattr)))) once.
// R18: blocks [nE8, nE8+65) run the W2f fuse concurrently — block fb<64:
// 4 output k-rows (coalesced Wn1_bot row loop, LDS-broadcast Wo rows);
// fb==64: b2f = bn1 + Wn1_bot^T bo. Written into Wn1t bottom + b2f,
// consumed by MLP1 far downstream.
__global__ __launch_bounds__(256) void estats_kernel(
    const float* __restrict__ eattr, const int* __restrict__ rowi,
    const int* __restrict__ coli, const float2* __restrict__ xs,
    const short* __restrict__ x_bf,
    const float* __restrict__ g1v, const float* __restrict__ b1v,
    short* __restrict__ e1n, int* __restrict__ counts,
    const float* __restrict__ Wo, const float* __restrict__ bo,
    const float* __restrict__ bn1, const float* __restrict__ Wn1raw,
    short* __restrict__ Wn1t, float* __restrict__ b2f, int nE8, int E)
{
    int t = threadIdx.x;
    if ((int)blockIdx.x >= nE8) {
        // -------- W2f fuse role --------
        int fb = blockIdx.x - nE8;
        __shared__ float wo[4][256];
        if (fb < 64) {
            #pragma unroll
            for (int i = 0; i < 4; i++) wo[i][t] = Wo[(size_t)(fb * 4 + i) * 256 + t];
        } else {
            wo[0][t] = bo[t];
        }
        __syncthreads();
        float a0 = 0.f, a1 = 0.f, a2 = 0.f, a3 = 0.f;
        if (fb < 64) {
            for (int j = 0; j < 256; j++) {
                float wn = Wn1raw[(size_t)(256 + j) * 256 + t];  // coalesced row
                a0 += wo[0][j] * wn; a1 += wo[1][j] * wn;
                a2 += wo[2][j] * wn; a3 += wo[3][j] * wn;
            }
            int k0 = fb * 4;
            Wn1t[(size_t)t * 512 + 256 + k0]     = f2bf(a0);
            Wn1t[(size_t)t * 512 + 256 + k0 + 1] = f2bf(a1);
            Wn1t[(size_t)t * 512 + 256 + k0 + 2] = f2bf(a2);
            Wn1t[(size_t)t * 512 + 256 + k0 + 3] = f2bf(a3);
        } else {
            for (int j = 0; j < 256; j++)
                a0 += wo[0][j] * Wn1raw[(size_t)(256 + j) * 256 + t];
            b2f[t] = bn1[t] + a0;
        }
        return;
    }
    __shared__ float2 ea[8][32];
    __shared__ float2 musr[8][32];
    int slot = t >> 5, g = t & 31;
    int e = blockIdx.x * 8 + slot;
    float4 a = *(const float4*)&eattr[(size_t)e * CH + g * 8];
    float4 b = *(const float4*)&eattr[(size_t)e * CH + g * 8 + 4];
    float s  = a.x + a.y + a.z + a.w + b.x + b.y + b.z + b.w;
    float s2 = a.x*a.x + a.y*a.y + a.z*a.z + a.w*a.w
             + b.x*b.x + b.y*b.y + b.z*b.z + b.w*b.w;
    ea[slot][g] = make_float2(s, s2);
    int r = rowi[e], c = coli[e];
    if (g == 0) atomicAdd(&counts[c], 1);
    __syncthreads();
    float S = 0.f, S2 = 0.f;
    #pragma unroll
    for (int j = 0; j < 3; j++) {
        int b3 = 3 * g + j;
        int src = b3 >> 5, idx = b3 & 31;
        float2 v;
        if (src == 0)      v = xs[(size_t)r * 32 + idx];
        else if (src == 1) v = xs[(size_t)c * 32 + idx];
        else               v = ea[slot][idx];
        S += v.x; S2 += v.y;
    }
    float m = S * (1.f / 24.f);
    float var = S2 * (1.f / 24.f) - m * m;
    musr[slot][g] = make_float2(m, rsqrtf(var + 1e-5f));
    __syncthreads();
    // normalize all 3 segments; 8-chunks never cross a group of 24
    #pragma unroll
    for (int seg = 0; seg < 3; seg++) {
        int pos = seg * 256 + g * 8;
        float2 ms = musr[slot][pos / 24];
        float4 ga  = *(const float4*)&g1v[pos];
        float4 ga2 = *(const float4*)&g1v[pos + 4];
        float4 gb  = *(const float4*)&b1v[pos];
        float4 gb2 = *(const float4*)&b1v[pos + 4];
        float v0, v1, v2, v3, v4, v5, v6, v7;
        if (seg == 2) {
            v0 = a.x; v1 = a.y; v2 = a.z; v3 = a.w;
            v4 = b.x; v5 = b.y; v6 = b.z; v7 = b.w;
        } else {
            const short* srow = x_bf + (size_t)(seg == 0 ? r : c) * CH + g * 8;
            short8 v8 = *(const short8*)srow;
            v0 = bf2f(v8[0]); v1 = bf2f(v8[1]); v2 = bf2f(v8[2]); v3 = bf2f(v8[3]);
            v4 = bf2f(v8[4]); v5 = bf2f(v8[5]); v6 = bf2f(v8[6]); v7 = bf2f(v8[7]);
        }
        short8 o;
        o[0] = f2bf(fmaxf((v0 - ms.x) * ms.y * ga.x  + gb.x,  0.f));
        o[1] = f2bf(fmaxf((v1 - ms.x) * ms.y * ga.y  + gb.y,  0.f));
        o[2] = f2bf(fmaxf((v2 - ms.x) * ms.y * ga.z  + gb.z,  0.f));
        o[3] = f2bf(fmaxf((v3 - ms.x) * ms.y * ga.w  + gb.w,  0.f));
        o[4] = f2bf(fmaxf((v4 - ms.x) * ms.y * ga2.x + gb2.x, 0.f));
        o[5] = f2bf(fmaxf((v5 - ms.x) * ms.y * ga2.y + gb2.y, 0.f));
        o[6] = f2bf(fmaxf((v6 - ms.x) * ms.y * ga2.z + gb2.z, 0.f));
        o[7] = f2bf(fmaxf((v7 - ms.x) * ms.y * ga2.w + gb2.w, 0.f));
        *(short8*)&e1n[(size_t)e * 768 + pos] = o;
    }
}

// ==================================================================== attention
// block = node; fused scoring (all 4 waves cooperate) + per-wave (=head)
// online softmax + PV. R16: writes straight into cat_bf right half
// (row stride 512) — feeds fused MLP1 without the Wo stage.
__global__ __launch_bounds__(256) void attn_kernel(
    const short* __restrict__ qb, const short* __restrict__ kvb,
    const int* __restrict__ offsets, const int* __restrict__ elist,
    const float* __restrict__ vbar, short* __restrict__ gout, int N, int E)
{
    __shared__ int eidx[64];
    __shared__ float scl[4 * 64];
    int n = blockIdx.x;
    int wave = threadIdx.x >> 6;
    int lane = threadIdx.x & 63;
    int s0 = offsets[n], s1 = offsets[n + 1];
    float q0 = bf2f(qb[(size_t)n * CH + lane]);
    float q1 = bf2f(qb[(size_t)n * CH + 64 + lane]);
    float q2 = bf2f(qb[(size_t)n * CH + 128 + lane]);
    float q3 = bf2f(qb[(size_t)n * CH + 192 + lane]);
    float out = 0.f, m = -INFINITY, l = 0.f;
    for (int base = s0; base < s1; base += 64) {
        int cn = s1 - base; if (cn > 64) cn = 64;
        if (wave == 0 && lane < cn) eidx[lane] = elist[base + lane];
        __syncthreads();
        for (int j = wave; j < cn; j += 4) {
            int e = eidx[j];
            const short* kr = kvb + (size_t)e * 512;
            float d0 = warp_sum64(q0 * bf2f(kr[lane]));
            float d1 = warp_sum64(q1 * bf2f(kr[64 + lane]));
            float d2 = warp_sum64(q2 * bf2f(kr[128 + lane]));
            float d3 = warp_sum64(q3 * bf2f(kr[192 + lane]));
            if (lane == 0) {
                scl[j]       = d0 * 0.125f;   // 1/sqrt(64)
                scl[64 + j]  = d1 * 0.125f;
                scl[128 + j] = d2 * 0.125f;
                scl[192 + j] = d3 * 0.125f;
            }
        }
        __syncthreads();
        float s = (lane < cn) ? scl[wave * 64 + lane] : -INFINITY;
        float mc = warp_max64(s);
        float nm = fmaxf(m, mc);
        float scale = __expf(m - nm);
        float pp = (lane < cn) ? __expf(s - nm) : 0.f;
        float ps = warp_sum64(pp);
        l = l * scale + ps;
        out *= scale;
        m = nm;
        for (int i = 0; i < cn; i++) {
            float pi = __shfl(pp, i, 64);
            int ei = eidx[i];
            out += pi * bf2f(kvb[(size_t)ei * 512 + 256 + wave * 64 + lane]);
        }
        __syncthreads();   // protect eidx/scl before next chunk
    }
    float res;
    if (s1 > s0) res = out / l;
    else         res = vbar[wave * 64 + lane] * (1.f / (float)E);  // uniform over all E
    gout[(size_t)n * 512 + wave * 64 + lane] = f2bf(res);
}

// ==================================================================== launch
extern "C" void kernel_launch(void* const* d_in, const int* in_sizes, int n_in,
                              void* d_out, int out_size, void* d_ws, size_t ws_size,
                              hipStream_t stream)
{
    const float* x       = (const float*)d_in[0];
    const int*   ei      = (const int*)d_in[1];
    const float* eattr   = (const float*)d_in[2];
    const float* gn_e1_g = (const float*)d_in[3];
    const float* gn_e1_b = (const float*)d_in[4];
    const float* We1     = (const float*)d_in[5];
    const float* be1     = (const float*)d_in[6];
    const float* gn_e2_g = (const float*)d_in[7];
    const float* gn_e2_b = (const float*)d_in[8];
    const float* We2     = (const float*)d_in[9];
    const float* be2     = (const float*)d_in[10];
    const float* gn_n_g  = (const float*)d_in[11];
    const float* gn_n_b  = (const float*)d_in[12];
    const float* Wq      = (const float*)d_in[13];
    const float* bq      = (const float*)d_in[14];
    const float* Wk      = (const float*)d_in[15];
    const float* bk      = (const float*)d_in[16];
    const float* Wv      = (const float*)d_in[17];
    const float* bv      = (const float*)d_in[18];
    const float* Wo      = (const float*)d_in[19];
    const float* bo      = (const float*)d_in[20];
    const float* Wn1     = (const float*)d_in[21];
    const float* bn1     = (const float*)d_in[22];
    const float* gn_n2_g = (const float*)d_in[23];
    const float* gn_n2_b = (const float*)d_in[24];
    const float* Wn2     = (const float*)d_in[25];
    const float* bn2     = (const float*)d_in[26];

    const int N = in_sizes[0] / CH;
    const int E = in_sizes[2] / CH;

    float* nout = (float*)d_out;
    float* eout = (float*)d_out + (size_t)N * CH;

    // ---- workspace ----
    char* base = (char*)d_ws;
    short* kv_bf  = (short*)base; base += (size_t)E * 512 * 2;
    short* h2_bf  = (short*)base; base += (size_t)E * CH * 2;
    short* eo_bf  = (short*)base; base += (size_t)E * CH * 2;
    short* e1n    = (short*)base; base += (size_t)E * 768 * 2;
    short* q_bf   = (short*)base; base += (size_t)N * CH * 2;
    short* g_bf   = (short*)base; base += (size_t)N * CH * 2;  // unused (layout kept)
    short* cat_bf = (short*)base; base += (size_t)N * 2 * CH * 2;
    short* hn_bf  = (short*)base; base += (size_t)N * CH * 2;
    short* x_bf   = (short*)base; base += (size_t)N * CH * 2;
    float2* xs    = (float2*)base; base += (size_t)N * 32 * 8;
    float* vbar   = (float*)base; base += 1024;
    float* bkv    = (float*)base; base += 2048;
    float* b2f    = (float*)base; base += 1024;
    short* We1t = (short*)base; base += (size_t)768 * 256 * 2;
    short* We2t = (short*)base; base += (size_t)256 * 256 * 2;
    short* Wqt  = (short*)base; base += (size_t)256 * 256 * 2;
    short* Wkvt = (short*)base; base += (size_t)512 * 256 * 2;
    short* Wn1t = (short*)base; base += (size_t)512 * 256 * 2;
    short* Wn2t = (short*)base; base += (size_t)256 * 256 * 2;
    int* counts  = (int*)base;
    int* offsets = counts + N;
    int* cursor  = offsets + (N + 1) + 3;
    int* elist   = cursor + N;

    const int* rowi = ei;
    const int* coli = ei + E;
    (void)g_bf;

    dim3 blk(256);

    // ---- merged prep (weights, x, counts) ----
    PrepPack pp;
    const float* wsrc[7] = {We1, We2, Wq, Wk, Wv, Wn1, Wn2};
    short* wdst[7] = {We1t, We2t, Wqt, Wkvt, Wkvt + (size_t)256 * 256, Wn1t, Wn2t};
    const int wKd[7] = {768, 256, 256, 256, 256, 512, 256};
    const int wEd[7] = {768, 256, 256, 256, 256, 256, 256};  // Wn1: top half only
    int acc = 0;
    for (int i = 0; i < 7; i++) {
        pp.wsrc[i] = wsrc[i]; pp.wdst[i] = wdst[i]; pp.wK[i] = wKd[i];
        pp.wstart[i] = acc; acc += wEd[i] / 16;
    }
    pp.NW = acc;
    pp.NP = (N + 7) / 8;
    pp.x = x; pp.x_bf = x_bf; pp.cat_bf = cat_bf; pp.xs = xs;
    pp.gng = gn_n_g; pp.gnb = gn_n_b;
    pp.vbar = vbar; pp.bk = bk; pp.bv = bv; pp.bkv = bkv;
    pp.counts = counts; pp.N = N;
    int nzero = (N + 255) / 256;
    prep_kernel<<<pp.NW + pp.NP + nzero, blk, 0, stream>>>(pp);

    // ---- estats + concurrent W2f fuse (65 extra blocks) ----
    int nE8 = E / 8;
    estats_kernel<<<nE8 + 65, blk, 0, stream>>>(eattr, rowi, coli, xs, x_bf,
                                                gn_e1_g, gn_e1_b, e1n, counts,
                                                Wo, bo, bn1, Wn1, Wn1t, b2f,
                                                nE8, E);

    GArgs ga = {};
    // ---- GEMM1: plain GEMM on e1n, K=768, XCD swizzle, +concurrent scan ----
    ga.A = e1n; ga.Bt = We1t; ga.bias = be1; ga.Cbf = h2_bf;
    ga.gamma = gn_e2_g; ga.beta = gn_e2_b;
    ga.M = E; ga.K = 3 * CH; ga.Nc = CH; ga.ldc = CH; ga.coff = 0;
    ga.counts = counts; ga.offsets = offsets; ga.cursor = cursor; ga.Nn = N;
    mfma_gemm<64, 64, 1, 0, 0, 0, 1, 0, 1><<<dim3(4, 257), blk, 0, stream>>>(ga);

    // ---- GEMM2: eout (f32, +eattr residual) + eo_bf, XCD swizzle ----
    ga = {};
    ga.A = h2_bf; ga.Bt = We2t; ga.bias = be2; ga.res = eattr;
    ga.C = eout; ga.Cbf = eo_bf;
    ga.M = E; ga.K = CH; ga.Nc = CH; ga.ldc = CH; ga.coff = 0;
    mfma_gemm<64, 64, 0, 0, 0, 0, 0, 0, 1><<<dim3(4, 256), blk, 0, stream>>>(ga);

    // ---- fused KV (2-panel, vbar, CSR fill, XCD swizzle) + Q in one launch ----
    ga = {};
    ga.A = eo_bf; ga.Bt = Wkvt; ga.bias = bkv; ga.Cbf = kv_bf; ga.vbar = vbar;
    ga.M = E; ga.K = CH; ga.Nc = 512; ga.ldc = 512; ga.coff = 0;
    ga.A2 = x_bf; ga.Bt2 = Wqt; ga.bias2 = bq; ga.Cbf2 = q_bf;
    ga.M2 = N; ga.Nc2 = CH; ga.y_split = 256;
    ga.coli = coli; ga.cursor = cursor; ga.elist = elist;
    mfma_gemm<64, 64, 0, 1, 1, 1, 0, 1, 1><<<dim3(4, 256 + (N + 63) / 64), blk, 0, stream>>>(ga);

    // ---- attention -> cat right half directly (Wo folded into MLP1) ----
    attn_kernel<<<N, blk, 0, stream>>>(q_bf, kv_bf, offsets, elist, vbar,
                                       cat_bf + 256, N, E);

    // ---- node MLP1 (fused weights: [Wn1_top; Wo@Wn1_bot], bias b2f) ----
    ga = {};
    ga.A = cat_bf; ga.Bt = Wn1t; ga.bias = b2f; ga.Cbf = hn_bf;
    ga.gamma = gn_n2_g; ga.beta = gn_n2_b;
    ga.M = N; ga.K = 2 * CH; ga.Nc = CH; ga.ldc = CH; ga.coff = 0;
    mfma_gemm<32, 64, 1, 0, 0, 0><<<dim3(4, (N + 31) / 32), blk, 0, stream>>>(ga);

    // ---- node MLP2 (+x residual, f32 out) ----
    ga = {};
    ga.A = hn_bf; ga.Bt = Wn2t; ga.bias = bn2; ga.res = x; ga.C = nout;
    ga.M = N; ga.K = CH; ga.Nc = CH; ga.ldc = CH; ga.coff = 0;
    mfma_gemm<32, 64, 0, 0, 0, 0><<<dim3(4, (N + 31) / 32), blk, 0, stream>>>(ga);
}

// Round 11
// 225.460 us; speedup vs baseline: 1.1497x; 1.0192x over previous
//
#include <hip/hip_runtime.h>
#include <hip/hip_bf16.h>
#include <stdint.h>
#include <math.h>

#define CH 256

typedef __attribute__((ext_vector_type(8)))  short short8;
typedef __attribute__((ext_vector_type(16))) short short16;
typedef __attribute__((ext_vector_type(4)))  float f32x4;

#define GL2LDS16(g, l) __builtin_amdgcn_global_load_lds(                       \
    (const __attribute__((address_space(1))) void*)(g),                        \
    (__attribute__((address_space(3))) void*)(l), 16, 0, 0)

__device__ inline short f2bf(float f) {
    __hip_bfloat16 h = __float2bfloat16(f);
    short s;
    __builtin_memcpy(&s, &h, 2);
    return s;
}

__device__ inline float bf2f(short s) {
    unsigned u = ((unsigned)(unsigned short)s) << 16;
    float f;
    __builtin_memcpy(&f, &u, 4);
    return f;
}

__device__ inline float warp_sum64(float v) {
    v += __shfl_xor(v, 32, 64);
    v += __shfl_xor(v, 16, 64);
    v += __shfl_xor(v, 8, 64);
    v += __shfl_xor(v, 4, 64);
    v += __shfl_xor(v, 2, 64);
    v += __shfl_xor(v, 1, 64);
    return v;
}

__device__ inline float warp_max64(float v) {
    v = fmaxf(v, __shfl_xor(v, 32, 64));
    v = fmaxf(v, __shfl_xor(v, 16, 64));
    v = fmaxf(v, __shfl_xor(v, 8, 64));
    v = fmaxf(v, __shfl_xor(v, 4, 64));
    v = fmaxf(v, __shfl_xor(v, 2, 64));
    v = fmaxf(v, __shfl_xor(v, 1, 64));
    return v;
}

// ==================================================================== MFMA GEMM
// BMxBN tile, BK=64, 2x2 wave grid, 16x16x32 bf16 MFMA. Single-buffer
// 2-barrier K-loop. R19 = R14 revert (Wo-fold arc R16-18 net-negative)
// + Q GEMM migrated from GEMM3's DUAL to GEMM1's DUAL (K2 per-role K):
// kills GEMM3's 128-block tail wave; Q backfills GEMM1's drain.
// EPI 1: GroupNorm(8 cols)+ReLU -> bf16 Cbf (edge role only; qrole plain).
// DUAL : blocks with by >= y_split run the Q GEMM (A2/Bt2/bias2/Cbf2, K2).
// VB   : V-panel column sums atomically into vbar (KV path).
// FILL : edge-role blocks with logical bx==0 scatter rows into elist.
// SCAN : last grid row runs the CSR prefix scan concurrently. [R11]
// PAN2 : block computes TWO output panels (cols c, c+256) per A staging. [R11]
// XSWZ : XCD-aware remap — ids {h,h+8,h+16,h+24} (same XCD under round-robin)
//        share logical row-panel lby -> A re-reads are L2 hits. [R14]
struct GArgs {
    const short* A; const short* Bt; const float* bias; const float* res;
    float* C; short* Cbf;
    const float* gamma; const float* beta; float* vbar;
    int M, K, Nc, ldc, coff;
    const short* A2; const short* Bt2; const float* bias2; short* Cbf2;
    int M2, Nc2, y_split, K2;
    const int* coli;
    int* cursor; int* elist;
    const int* counts; int* offsets; int Nn;   // SCAN role
};

template <int BM, int BN, int EPI, int DUAL, int VB, int FILL,
          int SCAN = 0, int PAN2 = 0, int XSWZ = 0>
__global__ __launch_bounds__(256) void mfma_gemm(GArgs g)
{
    constexpr int BK = 64;
    constexpr int HM = BM / 2, HN = BN / 2;
    constexpr int FM = HM / 16, FN = HN / 16;
    constexpr int PA = BM / 32;
    constexpr int PB = BN / 32;
    constexpr int NP2 = PAN2 ? 2 : 1;
    __shared__ short As[BM * BK];
    __shared__ short Bs[NP2 * BN * BK];

    const short* A = g.A; const short* Bt = g.Bt;
    const float* bias = g.bias; const float* res = g.res;
    float* C = g.C; short* Cbf = g.Cbf;
    int M = g.M, ldc = g.ldc, co = g.coff;
    int K = g.K;
    int by = blockIdx.y, bx = blockIdx.x;

    if constexpr (SCAN) {
        if (by == (int)gridDim.y - 1) {
            const int t0 = threadIdx.x;
            if (bx == 0) {
                int* ss = (int*)As;
                int base8 = t0 * 8;
                int loc[8]; int srun = 0;
                #pragma unroll
                for (int j = 0; j < 8; j++) {
                    int idx = base8 + j;
                    int c = (idx < g.Nn) ? g.counts[idx] : 0;
                    loc[j] = srun; srun += c;
                }
                ss[t0] = srun;
                __syncthreads();
                for (int off = 1; off < 256; off <<= 1) {
                    int v = (t0 >= off) ? ss[t0 - off] : 0;
                    __syncthreads();
                    ss[t0] += v;
                    __syncthreads();
                }
                int excl = (t0 > 0) ? ss[t0 - 1] : 0;
                #pragma unroll
                for (int j = 0; j < 8; j++) {
                    int idx = base8 + j;
                    if (idx < g.Nn) {
                        int v = excl + loc[j];
                        g.offsets[idx] = v;
                        g.cursor[idx]  = v;
                    }
                }
                if (t0 == 255) g.offsets[g.Nn] = ss[255];
            }
            return;
        }
    }

    bool qrole = false;
    if constexpr (DUAL) {
        if (by >= g.y_split) {
            by -= g.y_split;
            if (bx * BN >= g.Nc2) return;
            qrole = true;
            A = g.A2; Bt = g.Bt2; bias = g.bias2; Cbf = g.Cbf2;
            C = nullptr; res = nullptr;
            M = g.M2; ldc = g.Nc2; co = 0; K = g.K2;
        }
    }

    if constexpr (XSWZ) {
        if (!qrole) {
            int h = by * 4 + bx;               // gridDim.x == 4
            int lby = (h >> 5) * 8 + (h & 7);  // same-XCD ids share lby
            if (lby * BM >= M) return;         // guard padded rows
            by = lby;
            bx = (h >> 3) & 3;
        }
    }

    const int t = threadIdx.x;
    const int wave = t >> 6, lane = t & 63;
    const int q = lane >> 4, l16 = lane & 15;
    const int row0 = by * BM;
    const int col0 = bx * BN;
    const int wm = wave & 1, wn = wave >> 1;

    if constexpr (FILL) {
        if (!qrole && bx == 0 && t < BM) {
            int rg = row0 + t;
            if (rg < M) {
                int c = g.coli[rg];
                int p = atomicAdd(&g.cursor[c], 1);
                g.elist[p] = rg;
            }
        }
    }

    f32x4 acc[NP2][FM][FN];
    #pragma unroll
    for (int p2 = 0; p2 < NP2; p2++)
        #pragma unroll
        for (int i = 0; i < FM; i++)
            #pragma unroll
            for (int j = 0; j < FN; j++) acc[p2][i][j] = (f32x4){0.f, 0.f, 0.f, 0.f};

    for (int k0 = 0; k0 < K; k0 += BK) {
        #pragma unroll
        for (int p = 0; p < PA; p++) {
            int chunk = p * 256 + t;
            int r = chunk >> 3;
            int cs = (((chunk & 7) ^ (r & 7)) * 8);   // XOR bank swizzle
            int gr = row0 + r; if (gr >= M) gr = M - 1;
            const short* gsrc = A + (size_t)gr * K + k0 + cs;
            short* ldst = &As[(p * 256 + wave * 64) * 8];
            GL2LDS16(gsrc, ldst);
        }
        #pragma unroll
        for (int p2 = 0; p2 < NP2; p2++) {
            if (!(PAN2 && p2 == 1 && qrole)) {
                #pragma unroll
                for (int p = 0; p < PB; p++) {
                    int chunk = p * 256 + t;
                    int r = chunk >> 3;
                    int cs = (((chunk & 7) ^ (r & 7)) * 8);
                    const short* gsrc = Bt + (size_t)(col0 + p2 * 256 + r) * K + k0 + cs;
                    short* ldst = &Bs[p2 * BN * BK + (p * 256 + wave * 64) * 8];
                    GL2LDS16(gsrc, ldst);
                }
            }
        }
        __syncthreads();
        #pragma unroll
        for (int ks = 0; ks < 2; ks++) {
            short8 af[FM];
            #pragma unroll
            for (int mi = 0; mi < FM; mi++) {
                int R = wm * HM + mi * 16 + l16;
                int slot = ((ks * 4 + q) ^ (R & 7)) * 8;
                af[mi] = *(const short8*)&As[R * BK + slot];
            }
            #pragma unroll
            for (int p2 = 0; p2 < NP2; p2++) {
                if (!(PAN2 && p2 == 1 && qrole)) {
                    short8 bfr[FN];
                    #pragma unroll
                    for (int ni = 0; ni < FN; ni++) {
                        int R = wn * HN + ni * 16 + l16;
                        int slot = ((ks * 4 + q) ^ (R & 7)) * 8;
                        bfr[ni] = *(const short8*)&Bs[p2 * BN * BK + R * BK + slot];
                    }
                    #pragma unroll
                    for (int mi = 0; mi < FM; mi++)
                        #pragma unroll
                        for (int ni = 0; ni < FN; ni++)
                            acc[p2][mi][ni] = __builtin_amdgcn_mfma_f32_16x16x32_bf16(
                                af[mi], bfr[ni], acc[p2][mi][ni], 0, 0, 0);
                }
            }
        }
        __syncthreads();
    }

    // ---- epilogue; C/D layout: col = l16, row = q*4 + r ----
    #pragma unroll
    for (int p2 = 0; p2 < NP2; p2++) {
        if (PAN2 && p2 == 1 && qrole) continue;
        #pragma unroll
        for (int ni = 0; ni < FN; ni++) {
            int cg = col0 + p2 * 256 + wn * HN + ni * 16 + l16;
            float bv = bias[cg];
            if (EPI == 1 && !qrole) {
                float ga = g.gamma[cg], be = g.beta[cg];
                #pragma unroll
                for (int mi = 0; mi < FM; mi++) {
                    #pragma unroll
                    for (int r = 0; r < 4; r++) {
                        float v = acc[p2][mi][ni][r] + bv;
                        float s = v, sq = v * v;
                        s += __shfl_xor(s, 1, 64);  sq += __shfl_xor(sq, 1, 64);
                        s += __shfl_xor(s, 2, 64);  sq += __shfl_xor(sq, 2, 64);
                        s += __shfl_xor(s, 4, 64);  sq += __shfl_xor(sq, 4, 64);
                        float mean = s * 0.125f;
                        float var = sq * 0.125f - mean * mean;
                        float o = fmaxf((v - mean) * rsqrtf(var + 1e-5f) * ga + be, 0.f);
                        int rg = row0 + wm * HM + mi * 16 + q * 4 + r;
                        if (rg < M) Cbf[(size_t)rg * ldc + co + cg] = f2bf(o);
                    }
                }
            } else {
                #pragma unroll
                for (int mi = 0; mi < FM; mi++) {
                    #pragma unroll
                    for (int r = 0; r < 4; r++) {
                        int rg = row0 + wm * HM + mi * 16 + q * 4 + r;
                        if (rg < M) {
                            float v = acc[p2][mi][ni][r] + bv;
                            if (res) v += res[(size_t)rg * ldc + co + cg];
                            if (C)   C[(size_t)rg * ldc + co + cg] = v;
                            if (Cbf) Cbf[(size_t)rg * ldc + co + cg] = f2bf(v);
                        }
                    }
                }
                if constexpr (VB) {
                    bool vpanel = PAN2 ? (p2 == 1) : (!qrole && cg >= 256);
                    if (vpanel && !qrole) {
                        float part = 0.f;
                        #pragma unroll
                        for (int mi = 0; mi < FM; mi++)
                            #pragma unroll
                            for (int r = 0; r < 4; r++) {
                                int rg = row0 + wm * HM + mi * 16 + q * 4 + r;
                                if (rg < M) part += acc[p2][mi][ni][r] + bv;
                            }
                        part += __shfl_xor(part, 16, 64);
                        part += __shfl_xor(part, 32, 64);
                        if (q == 0) atomicAdd(&g.vbar[cg - 256], part);
                    }
                }
            }
        }
    }
}

// ==================================================================== merged prep
struct PrepPack {
    const float* wsrc[8];
    short* wdst[8];
    int wK[8];
    int wstart[8];
    int NW, NP;
    const float* x;
    short* x_bf;
    short* cat_bf;
    float2* xs;
    const float* gng;
    const float* gnb;
    float* vbar;
    const float* bk;
    const float* bv;
    float* bkv;
    int* counts;
    int N;
};

__global__ __launch_bounds__(256) void prep_kernel(PrepPack p)
{
    int bid = blockIdx.x;
    int t = threadIdx.x;
    if (bid < p.NW) {
        int m = 0;
        #pragma unroll
        for (int i = 1; i < 8; i++) if (bid >= p.wstart[i]) m = i;
        int k0 = (bid - p.wstart[m]) * 16;
        const float* src = p.wsrc[m];
        short16 o;
        #pragma unroll
        for (int j = 0; j < 16; j++) o[j] = f2bf(src[(size_t)(k0 + j) * 256 + t]);
        *(short16*)(p.wdst[m] + (size_t)t * p.wK[m] + k0) = o;
        return;
    }
    if (bid >= p.NW + p.NP) {
        int i = (bid - p.NW - p.NP) * 256 + t;
        if (i < p.N) p.counts[i] = 0;
        return;
    }
    int pb = bid - p.NW;
    if (pb == 0) {
        p.vbar[t] = 0.f;
        p.bkv[t] = p.bk[t];
        p.bkv[256 + t] = p.bv[t];
    }
    int r = pb * 8 + (t >> 5);
    int g = t & 31;
    if (r >= p.N) return;
    size_t xb = (size_t)r * CH + g * 8;
    float4 a = *(const float4*)&p.x[xb];
    float4 b = *(const float4*)&p.x[xb + 4];
    short8 xr;
    xr[0] = f2bf(a.x); xr[1] = f2bf(a.y); xr[2] = f2bf(a.z); xr[3] = f2bf(a.w);
    xr[4] = f2bf(b.x); xr[5] = f2bf(b.y); xr[6] = f2bf(b.z); xr[7] = f2bf(b.w);
    *(short8*)&p.x_bf[xb] = xr;
    float s  = a.x + a.y + a.z + a.w + b.x + b.y + b.z + b.w;
    float s2 = a.x*a.x + a.y*a.y + a.z*a.z + a.w*a.w
             + b.x*b.x + b.y*b.y + b.z*b.z + b.w*b.w;
    p.xs[(size_t)r * 32 + g] = make_float2(s, s2);
    float m = s * 0.125f;
    float var = s2 * 0.125f - m * m;
    float rsd = rsqrtf(var + 1e-5f);
    float4 g0 = *(const float4*)&p.gng[g * 8];
    float4 g1 = *(const float4*)&p.gng[g * 8 + 4];
    float4 b0 = *(const float4*)&p.gnb[g * 8];
    float4 b1 = *(const float4*)&p.gnb[g * 8 + 4];
    short8 o;
    o[0] = f2bf(fmaxf((a.x - m) * rsd * g0.x + b0.x, 0.f));
    o[1] = f2bf(fmaxf((a.y - m) * rsd * g0.y + b0.y, 0.f));
    o[2] = f2bf(fmaxf((a.z - m) * rsd * g0.z + b0.z, 0.f));
    o[3] = f2bf(fmaxf((a.w - m) * rsd * g0.w + b0.w, 0.f));
    o[4] = f2bf(fmaxf((b.x - m) * rsd * g1.x + b1.x, 0.f));
    o[5] = f2bf(fmaxf((b.y - m) * rsd * g1.y + b1.y, 0.f));
    o[6] = f2bf(fmaxf((b.z - m) * rsd * g1.z + b1.z, 0.f));
    o[7] = f2bf(fmaxf((b.w - m) * rsd * g1.w + b1.w, 0.f));
    *(short8*)&p.cat_bf[(size_t)r * (2 * CH) + g * 8] = o;
}

// ==================================================================== edge stats
// R13: computes group stats AND materializes the full normalized edge-MLP
// input e1n[E][768] = bf16(relu(gn_g24(cat(x[row], x[col], eattr)))) once.
__global__ __launch_bounds__(256) void estats_kernel(
    const float* __restrict__ eattr, const int* __restrict__ rowi,
    const int* __restrict__ coli, const float2* __restrict__ xs,
    const short* __restrict__ x_bf,
    const float* __restrict__ g1v, const float* __restrict__ b1v,
    short* __restrict__ e1n, int* __restrict__ counts, int E)
{
    __shared__ float2 ea[8][32];
    __shared__ float2 musr[8][32];
    int t = threadIdx.x;
    int slot = t >> 5, g = t & 31;
    int e = blockIdx.x * 8 + slot;
    float4 a = *(const float4*)&eattr[(size_t)e * CH + g * 8];
    float4 b = *(const float4*)&eattr[(size_t)e * CH + g * 8 + 4];
    float s  = a.x + a.y + a.z + a.w + b.x + b.y + b.z + b.w;
    float s2 = a.x*a.x + a.y*a.y + a.z*a.z + a.w*a.w
             + b.x*b.x + b.y*b.y + b.z*b.z + b.w*b.w;
    ea[slot][g] = make_float2(s, s2);
    int r = rowi[e], c = coli[e];
    if (g == 0) atomicAdd(&counts[c], 1);
    __syncthreads();
    float S = 0.f, S2 = 0.f;
    #pragma unroll
    for (int j = 0; j < 3; j++) {
        int b3 = 3 * g + j;
        int src = b3 >> 5, idx = b3 & 31;
        float2 v;
        if (src == 0)      v = xs[(size_t)r * 32 + idx];
        else if (src == 1) v = xs[(size_t)c * 32 + idx];
        else               v = ea[slot][idx];
        S += v.x; S2 += v.y;
    }
    float m = S * (1.f / 24.f);
    float var = S2 * (1.f / 24.f) - m * m;
    musr[slot][g] = make_float2(m, rsqrtf(var + 1e-5f));
    __syncthreads();
    // normalize all 3 segments; 8-chunks never cross a group of 24
    #pragma unroll
    for (int seg = 0; seg < 3; seg++) {
        int pos = seg * 256 + g * 8;
        float2 ms = musr[slot][pos / 24];
        float4 ga  = *(const float4*)&g1v[pos];
        float4 ga2 = *(const float4*)&g1v[pos + 4];
        float4 gb  = *(const float4*)&b1v[pos];
        float4 gb2 = *(const float4*)&b1v[pos + 4];
        float v0, v1, v2, v3, v4, v5, v6, v7;
        if (seg == 2) {
            v0 = a.x; v1 = a.y; v2 = a.z; v3 = a.w;
            v4 = b.x; v5 = b.y; v6 = b.z; v7 = b.w;
        } else {
            const short* srow = x_bf + (size_t)(seg == 0 ? r : c) * CH + g * 8;
            short8 v8 = *(const short8*)srow;
            v0 = bf2f(v8[0]); v1 = bf2f(v8[1]); v2 = bf2f(v8[2]); v3 = bf2f(v8[3]);
            v4 = bf2f(v8[4]); v5 = bf2f(v8[5]); v6 = bf2f(v8[6]); v7 = bf2f(v8[7]);
        }
        short8 o;
        o[0] = f2bf(fmaxf((v0 - ms.x) * ms.y * ga.x  + gb.x,  0.f));
        o[1] = f2bf(fmaxf((v1 - ms.x) * ms.y * ga.y  + gb.y,  0.f));
        o[2] = f2bf(fmaxf((v2 - ms.x) * ms.y * ga.z  + gb.z,  0.f));
        o[3] = f2bf(fmaxf((v3 - ms.x) * ms.y * ga.w  + gb.w,  0.f));
        o[4] = f2bf(fmaxf((v4 - ms.x) * ms.y * ga2.x + gb2.x, 0.f));
        o[5] = f2bf(fmaxf((v5 - ms.x) * ms.y * ga2.y + gb2.y, 0.f));
        o[6] = f2bf(fmaxf((v6 - ms.x) * ms.y * ga2.z + gb2.z, 0.f));
        o[7] = f2bf(fmaxf((v7 - ms.x) * ms.y * ga2.w + gb2.w, 0.f));
        *(short8*)&e1n[(size_t)e * 768 + pos] = o;
    }
}

// ==================================================================== attention
// block = node; fused scoring (all 4 waves cooperate) + per-wave (=head)
// online softmax + PV. Scores never touch global memory.
__global__ __launch_bounds__(256) void attn_kernel(
    const short* __restrict__ qb, const short* __restrict__ kvb,
    const int* __restrict__ offsets, const int* __restrict__ elist,
    const float* __restrict__ vbar, short* __restrict__ g_bf, int N, int E)
{
    __shared__ int eidx[64];
    __shared__ float scl[4 * 64];
    int n = blockIdx.x;
    int wave = threadIdx.x >> 6;
    int lane = threadIdx.x & 63;
    int s0 = offsets[n], s1 = offsets[n + 1];
    float q0 = bf2f(qb[(size_t)n * CH + lane]);
    float q1 = bf2f(qb[(size_t)n * CH + 64 + lane]);
    float q2 = bf2f(qb[(size_t)n * CH + 128 + lane]);
    float q3 = bf2f(qb[(size_t)n * CH + 192 + lane]);
    float out = 0.f, m = -INFINITY, l = 0.f;
    for (int base = s0; base < s1; base += 64) {
        int cn = s1 - base; if (cn > 64) cn = 64;
        if (wave == 0 && lane < cn) eidx[lane] = elist[base + lane];
        __syncthreads();
        for (int j = wave; j < cn; j += 4) {
            int e = eidx[j];
            const short* kr = kvb + (size_t)e * 512;
            float d0 = warp_sum64(q0 * bf2f(kr[lane]));
            float d1 = warp_sum64(q1 * bf2f(kr[64 + lane]));
            float d2 = warp_sum64(q2 * bf2f(kr[128 + lane]));
            float d3 = warp_sum64(q3 * bf2f(kr[192 + lane]));
            if (lane == 0) {
                scl[j]       = d0 * 0.125f;   // 1/sqrt(64)
                scl[64 + j]  = d1 * 0.125f;
                scl[128 + j] = d2 * 0.125f;
                scl[192 + j] = d3 * 0.125f;
            }
        }
        __syncthreads();
        float s = (lane < cn) ? scl[wave * 64 + lane] : -INFINITY;
        float mc = warp_max64(s);
        float nm = fmaxf(m, mc);
        float scale = __expf(m - nm);
        float pp = (lane < cn) ? __expf(s - nm) : 0.f;
        float ps = warp_sum64(pp);
        l = l * scale + ps;
        out *= scale;
        m = nm;
        for (int i = 0; i < cn; i++) {
            float pi = __shfl(pp, i, 64);
            int ei = eidx[i];
            out += pi * bf2f(kvb[(size_t)ei * 512 + 256 + wave * 64 + lane]);
        }
        __syncthreads();   // protect eidx/scl before next chunk
    }
    float res;
    if (s1 > s0) res = out / l;
    else         res = vbar[wave * 64 + lane] * (1.f / (float)E);  // uniform over all E
    g_bf[(size_t)n * CH + wave * 64 + lane] = f2bf(res);
}

// ==================================================================== launch
extern "C" void kernel_launch(void* const* d_in, const int* in_sizes, int n_in,
                              void* d_out, int out_size, void* d_ws, size_t ws_size,
                              hipStream_t stream)
{
    const float* x       = (const float*)d_in[0];
    const int*   ei      = (const int*)d_in[1];
    const float* eattr   = (const float*)d_in[2];
    const float* gn_e1_g = (const float*)d_in[3];
    const float* gn_e1_b = (const float*)d_in[4];
    const float* We1     = (const float*)d_in[5];
    const float* be1     = (const float*)d_in[6];
    const float* gn_e2_g = (const float*)d_in[7];
    const float* gn_e2_b = (const float*)d_in[8];
    const float* We2     = (const float*)d_in[9];
    const float* be2     = (const float*)d_in[10];
    const float* gn_n_g  = (const float*)d_in[11];
    const float* gn_n_b  = (const float*)d_in[12];
    const float* Wq      = (const float*)d_in[13];
    const float* bq      = (const float*)d_in[14];
    const float* Wk      = (const float*)d_in[15];
    const float* bk      = (const float*)d_in[16];
    const float* Wv      = (const float*)d_in[17];
    const float* bv      = (const float*)d_in[18];
    const float* Wo      = (const float*)d_in[19];
    const float* bo      = (const float*)d_in[20];
    const float* Wn1     = (const float*)d_in[21];
    const float* bn1     = (const float*)d_in[22];
    const float* gn_n2_g = (const float*)d_in[23];
    const float* gn_n2_b = (const float*)d_in[24];
    const float* Wn2     = (const float*)d_in[25];
    const float* bn2     = (const float*)d_in[26];

    const int N = in_sizes[0] / CH;
    const int E = in_sizes[2] / CH;

    float* nout = (float*)d_out;
    float* eout = (float*)d_out + (size_t)N * CH;

    // ---- workspace ----
    char* base = (char*)d_ws;
    short* kv_bf  = (short*)base; base += (size_t)E * 512 * 2;
    short* h2_bf  = (short*)base; base += (size_t)E * CH * 2;
    short* eo_bf  = (short*)base; base += (size_t)E * CH * 2;
    short* e1n    = (short*)base; base += (size_t)E * 768 * 2;
    short* q_bf   = (short*)base; base += (size_t)N * CH * 2;
    short* g_bf   = (short*)base; base += (size_t)N * CH * 2;
    short* cat_bf = (short*)base; base += (size_t)N * 2 * CH * 2;
    short* hn_bf  = (short*)base; base += (size_t)N * CH * 2;
    short* x_bf   = (short*)base; base += (size_t)N * CH * 2;
    float2* xs    = (float2*)base; base += (size_t)N * 32 * 8;
    float* vbar   = (float*)base; base += 1024;
    float* bkv    = (float*)base; base += 2048;
    short* We1t = (short*)base; base += (size_t)768 * 256 * 2;
    short* We2t = (short*)base; base += (size_t)256 * 256 * 2;
    short* Wqt  = (short*)base; base += (size_t)256 * 256 * 2;
    short* Wkvt = (short*)base; base += (size_t)512 * 256 * 2;
    short* Wot  = (short*)base; base += (size_t)256 * 256 * 2;
    short* Wn1t = (short*)base; base += (size_t)512 * 256 * 2;
    short* Wn2t = (short*)base; base += (size_t)256 * 256 * 2;
    int* counts  = (int*)base;
    int* offsets = counts + N;
    int* cursor  = offsets + (N + 1) + 3;
    int* elist   = cursor + N;

    const int* rowi = ei;
    const int* coli = ei + E;

    dim3 blk(256);

    // ---- merged prep ----
    PrepPack pp;
    const float* wsrc[8] = {We1, We2, Wq, Wk, Wv, Wo, Wn1, Wn2};
    short* wdst[8] = {We1t, We2t, Wqt, Wkvt, Wkvt + (size_t)256 * 256, Wot, Wn1t, Wn2t};
    const int wKd[8] = {768, 256, 256, 256, 256, 256, 512, 256};
    int acc = 0;
    for (int i = 0; i < 8; i++) {
        pp.wsrc[i] = wsrc[i]; pp.wdst[i] = wdst[i]; pp.wK[i] = wKd[i];
        pp.wstart[i] = acc; acc += wKd[i] / 16;
    }
    pp.NW = acc;
    pp.NP = (N + 7) / 8;
    pp.x = x; pp.x_bf = x_bf; pp.cat_bf = cat_bf; pp.xs = xs;
    pp.gng = gn_n_g; pp.gnb = gn_n_b;
    pp.vbar = vbar; pp.bk = bk; pp.bv = bv; pp.bkv = bkv;
    pp.counts = counts; pp.N = N;
    int nzero = (N + 255) / 256;
    prep_kernel<<<pp.NW + pp.NP + nzero, blk, 0, stream>>>(pp);

    estats_kernel<<<E / 8, blk, 0, stream>>>(eattr, rowi, coli, xs, x_bf,
                                             gn_e1_g, gn_e1_b, e1n, counts, E);

    GArgs ga = {};
    // ---- GEMM1: e1n GEMM (K=768) + Q GEMM (DUAL, K2=256) + scan row ----
    ga.A = e1n; ga.Bt = We1t; ga.bias = be1; ga.Cbf = h2_bf;
    ga.gamma = gn_e2_g; ga.beta = gn_e2_b;
    ga.M = E; ga.K = 3 * CH; ga.Nc = CH; ga.ldc = CH; ga.coff = 0;
    ga.A2 = x_bf; ga.Bt2 = Wqt; ga.bias2 = bq; ga.Cbf2 = q_bf;
    ga.M2 = N; ga.Nc2 = CH; ga.y_split = 256; ga.K2 = CH;
    ga.counts = counts; ga.offsets = offsets; ga.cursor = cursor; ga.Nn = N;
    mfma_gemm<64, 64, 1, 1, 0, 0, 1, 0, 1>
        <<<dim3(4, 256 + (N + 63) / 64 + 1), blk, 0, stream>>>(ga);

    // ---- GEMM2: eout (f32, +eattr residual) + eo_bf, XCD swizzle ----
    ga = {};
    ga.A = h2_bf; ga.Bt = We2t; ga.bias = be2; ga.res = eattr;
    ga.C = eout; ga.Cbf = eo_bf;
    ga.M = E; ga.K = CH; ga.Nc = CH; ga.ldc = CH; ga.coff = 0;
    mfma_gemm<64, 64, 0, 0, 0, 0, 0, 0, 1><<<dim3(4, 256), blk, 0, stream>>>(ga);

    // ---- GEMM3: pure KV (2-panel, vbar, CSR fill, XCD swizzle), no tail ----
    ga = {};
    ga.A = eo_bf; ga.Bt = Wkvt; ga.bias = bkv; ga.Cbf = kv_bf; ga.vbar = vbar;
    ga.M = E; ga.K = CH; ga.Nc = 512; ga.ldc = 512; ga.coff = 0;
    ga.coli = coli; ga.cursor = cursor; ga.elist = elist;
    mfma_gemm<64, 64, 0, 0, 1, 1, 0, 1, 1><<<dim3(4, 256), blk, 0, stream>>>(ga);

    // ---- attention (scores fused in) ----
    attn_kernel<<<N, blk, 0, stream>>>(q_bf, kv_bf, offsets, elist, vbar, g_bf, N, E);

    // ---- Wo -> cat right half (bf16) ----
    ga = {};
    ga.A = g_bf; ga.Bt = Wot; ga.bias = bo; ga.Cbf = cat_bf;
    ga.M = N; ga.K = CH; ga.Nc = CH; ga.ldc = 2 * CH; ga.coff = CH;
    mfma_gemm<32, 64, 0, 0, 0, 0><<<dim3(4, (N + 31) / 32), blk, 0, stream>>>(ga);

    // ---- node MLP ----
    ga = {};
    ga.A = cat_bf; ga.Bt = Wn1t; ga.bias = bn1; ga.Cbf = hn_bf;
    ga.gamma = gn_n2_g; ga.beta = gn_n2_b;
    ga.M = N; ga.K = 2 * CH; ga.Nc = CH; ga.ldc = CH; ga.coff = 0;
    mfma_gemm<32, 64, 1, 0, 0, 0><<<dim3(4, (N + 31) / 32), blk, 0, stream>>>(ga);

    ga = {};
    ga.A = hn_bf; ga.Bt = Wn2t; ga.bias = bn2; ga.res = x; ga.C = nout;
    ga.M = N; ga.K = CH; ga.Nc = CH; ga.ldc = CH; ga.coff = 0;
    mfma_gemm<32, 64, 0, 0, 0, 0><<<dim3(4, (N + 31) / 32), blk, 0, stream>>>(ga);
}